// Round 1
// baseline (623.078 us; speedup 1.0000x reference)
//
#include <hip/hip_runtime.h>

// ROI-Align 2.5D on MI355X.
// fea: (B=16, C=64, H=128, W=128, D=8) fp32
// keypoints: (16, 5, 3) fp32 (z unused)
// out: (16, 5, 64, 2, 2, 8) fp32  -> 163840 elems
//
// Separable formulation: per (roi, bin) accumulate per-row weights Wy[r]
// (sum over gh adaptive samples of bilinear y-weights / gh) and per-col
// weights Wx[x] (/gw). Then out[c,d] = sum_r sum_x Wy[r]*Wx[x]*fea[...].
// Validity masks in the reference are provably always true for this config
// (coords in [0, 128], -1 <= ys <= h), so they are omitted.

#define CC 64
#define HH 128
#define WW 128
#define DD 8
#define CS 16.0f   // int(H * 1/8)

__global__ __launch_bounds__(256) void roi_align_25d_kernel(
    const float* __restrict__ fea,
    const float* __restrict__ kp,
    float* __restrict__ out)
{
    __shared__ float wy[20];
    __shared__ float wx[20];
    __shared__ int s_ry0, s_rx0, s_nr, s_nc;

    const int bx  = blockIdx.x;      // 0..319
    const int roi = bx >> 2;         // 0..79
    const int ph  = (bx >> 1) & 1;
    const int pw  = bx & 1;
    const int b   = roi / 5;
    const int tid = threadIdx.x;

    if (tid < 20) { wy[tid] = 0.0f; wx[tid] = 0.0f; }
    __syncthreads();

    if (tid == 0) {
        // ---- y axis ----
        float ky   = kp[roi * 3 + 1] * (float)HH;
        float ymin = fminf(fmaxf(ky - CS, 0.0f), (float)(HH - 1));
        float ymax = fminf(fmaxf(ky + CS, 0.0f), (float)(HH - 1));
        float roih = fmaxf(ymax - ymin, 1.0f);
        float binh = roih * 0.5f;
        int   gh   = (int)ceilf(roih * 0.5f);
        float step = binh / (float)gh;
        float start = ymin + (float)ph * binh;
        float y0   = start + 0.5f * step;
        int   ry0  = (int)floorf(y0);
        if (ry0 > HH - 1) ry0 = HH - 1;
        float inv  = 1.0f / (float)gh;
        int maxr = ry0;
        for (int i = 0; i < gh; ++i) {
            float ys = start + ((float)i + 0.5f) * step;
            int l0 = (int)floorf(ys);
            if (l0 >= HH - 1) {
                wy[(HH - 1) - ry0] += inv;
                if (HH - 1 > maxr) maxr = HH - 1;
            } else {
                float fr = ys - (float)l0;
                wy[l0 - ry0]     += (1.0f - fr) * inv;
                wy[l0 + 1 - ry0] += fr * inv;
                if (l0 + 1 > maxr) maxr = l0 + 1;
            }
        }
        s_ry0 = ry0;
        s_nr  = maxr - ry0 + 1;
    } else if (tid == 64) {
        // ---- x axis ----
        float kx   = kp[roi * 3 + 0] * (float)WW;
        float xmin = fminf(fmaxf(kx - CS, 0.0f), (float)(WW - 1));
        float xmax = fminf(fmaxf(kx + CS, 0.0f), (float)(WW - 1));
        float roiw = fmaxf(xmax - xmin, 1.0f);
        float binw = roiw * 0.5f;
        int   gw   = (int)ceilf(roiw * 0.5f);
        float step = binw / (float)gw;
        float start = xmin + (float)pw * binw;
        float x0   = start + 0.5f * step;
        int   rx0  = (int)floorf(x0);
        if (rx0 > WW - 1) rx0 = WW - 1;
        float inv  = 1.0f / (float)gw;
        int maxc = rx0;
        for (int i = 0; i < gw; ++i) {
            float xs = start + ((float)i + 0.5f) * step;
            int l0 = (int)floorf(xs);
            if (l0 >= WW - 1) {
                wx[(WW - 1) - rx0] += inv;
                if (WW - 1 > maxc) maxc = WW - 1;
            } else {
                float fr = xs - (float)l0;
                wx[l0 - rx0]     += (1.0f - fr) * inv;
                wx[l0 + 1 - rx0] += fr * inv;
                if (l0 + 1 > maxc) maxc = l0 + 1;
            }
        }
        s_rx0 = rx0;
        s_nc  = maxc - rx0 + 1;
    }
    __syncthreads();

    const int c  = tid >> 2;   // 0..63
    const int dp = tid & 3;    // 0..3  (float2 over D=8)

    const int ry0 = s_ry0, rx0 = s_rx0, nr = s_nr, nc = s_nc;

    const float* base = fea
        + (((size_t)(b * CC + c) * HH + ry0) * WW + rx0) * DD
        + dp * 2;

    float ax = 0.0f, ay = 0.0f;
    for (int r = 0; r < nr; ++r) {
        float wyr = wy[r];
        const float* pr = base + (size_t)r * (WW * DD);
        #pragma unroll 4
        for (int j = 0; j < nc; ++j) {
            float w = wyr * wx[j];
            float2 v = *reinterpret_cast<const float2*>(pr + j * DD);
            ax = fmaf(w, v.x, ax);
            ay = fmaf(w, v.y, ay);
        }
    }

    float2 o; o.x = ax; o.y = ay;
    *reinterpret_cast<float2*>(
        out + ((((size_t)roi * CC + c) * 2 + ph) * 2 + pw) * DD + dp * 2) = o;
}

extern "C" void kernel_launch(void* const* d_in, const int* in_sizes, int n_in,
                              void* d_out, int out_size, void* d_ws, size_t ws_size,
                              hipStream_t stream) {
    const float* fea = (const float*)d_in[0];
    const float* kp  = (const float*)d_in[1];
    float* out = (float*)d_out;
    (void)in_sizes; (void)n_in; (void)out_size; (void)d_ws; (void)ws_size;

    roi_align_25d_kernel<<<320, 256, 0, stream>>>(fea, kp, out);
}